// Round 1
// baseline (1590.770 us; speedup 1.0000x reference)
//
#include <hip/hip_runtime.h>
#include <hip/hip_bf16.h>

#define NN 50000
#define EE 500000
#define GG 64
#define IN_F 128
#define H_F 64
#define HEADS 4
#define OUT_F 326000
#define NEG 0.2f

// ---------------- embedding GEMM: h0 = x @ W_emb + b_emb ----------------
// W_emb staged in LDS (32 KB). Block = 256 threads = 4 waves; each wave owns 8
// consecutive nodes; lane = output channel. x rows read as wave-uniform float4
// broadcasts (readfirstlane -> scalar loads). No per-thread weight array -> no spill.
__global__ __launch_bounds__(256) void k_emb(const float* __restrict__ x,
                                             const float* __restrict__ Wemb,
                                             const float* __restrict__ bemb,
                                             float* __restrict__ h0) {
    __shared__ float wlds[IN_F * H_F];  // [k][c], 32 KB
    int t = threadIdx.x;
#pragma unroll
    for (int i = 0; i < (IN_F * H_F) / (4 * 256); ++i)  // 8 float4 per thread
        ((float4*)wlds)[t + 256 * i] = ((const float4*)Wemb)[t + 256 * i];
    __syncthreads();

    int c = t & 63, sub = t >> 6;
    int n0 = __builtin_amdgcn_readfirstlane(blockIdx.x * 32 + sub * 8);
    float bv = bemb[c];

    if (n0 + 8 <= NN) {
        const float4* xr = (const float4*)(x + (size_t)n0 * IN_F);
        float acc[8] = {0.f, 0.f, 0.f, 0.f, 0.f, 0.f, 0.f, 0.f};
        for (int k4 = 0; k4 < IN_F / 4; ++k4) {
            float w0 = wlds[(4 * k4 + 0) * H_F + c];
            float w1 = wlds[(4 * k4 + 1) * H_F + c];
            float w2 = wlds[(4 * k4 + 2) * H_F + c];
            float w3 = wlds[(4 * k4 + 3) * H_F + c];
#pragma unroll
            for (int j = 0; j < 8; ++j) {
                float4 xv = xr[j * (IN_F / 4) + k4];  // wave-uniform 16B broadcast
                acc[j] = fmaf(xv.x, w0,
                         fmaf(xv.y, w1,
                         fmaf(xv.z, w2,
                         fmaf(xv.w, w3, acc[j]))));
            }
        }
#pragma unroll
        for (int j = 0; j < 8; ++j)
            h0[(size_t)(n0 + j) * H_F + c] = acc[j] + bv;
    } else {
        // tail (never taken for NN % 8 == 0, kept for safety)
        for (int j = 0; j < 8; ++j) {
            int n = n0 + j;
            if (n >= NN) break;
            const float* xrow = x + (size_t)n * IN_F;
            float a = 0.f;
            for (int k = 0; k < IN_F; ++k) a += xrow[k] * wlds[k * H_F + c];
            h0[(size_t)n * H_F + c] = a + bv;
        }
    }
}

// ---------------- per-layer GEMM: xbuf = h @ W, plus ls/ld via wave reduce ----
// W (64 KB) staged in LDS. Block = 256 threads = all 256 output cols; processes
// 4 nodes per pass with block-uniform float4 h-row loads. wave w = head w.
__global__ __launch_bounds__(256) void k_gemm_layer(const float* __restrict__ h,
                                                    const float* __restrict__ W,
                                                    const float* __restrict__ a_src,
                                                    const float* __restrict__ a_dst,
                                                    float* __restrict__ xbuf,
                                                    float* __restrict__ ls,
                                                    float* __restrict__ ld) {
    __shared__ float wlds[H_F * HEADS * H_F];  // [k][t], 64 KB
    int t = threadIdx.x;
#pragma unroll
    for (int i = 0; i < (H_F * HEADS * H_F) / (4 * 256); ++i)  // 16 float4 per thread
        ((float4*)wlds)[t + 256 * i] = ((const float4*)W)[t + 256 * i];
    float asv = a_src[t], adv = a_dst[t];
    __syncthreads();

    int lane = t & 63, wv = t >> 6;
    int base = blockIdx.x * 32;
    for (int ii = 0; ii < 32; ii += 4) {
        int n0 = base + ii;
        if (n0 >= NN) return;  // NN % 4 == 0 -> groups are always full
        const float4* hb = (const float4*)(h + (size_t)n0 * H_F);
        float acc[4] = {0.f, 0.f, 0.f, 0.f};
        for (int k4 = 0; k4 < H_F / 4; ++k4) {
            float w0 = wlds[(4 * k4 + 0) * (HEADS * H_F) + t];
            float w1 = wlds[(4 * k4 + 1) * (HEADS * H_F) + t];
            float w2 = wlds[(4 * k4 + 2) * (HEADS * H_F) + t];
            float w3 = wlds[(4 * k4 + 3) * (HEADS * H_F) + t];
#pragma unroll
            for (int j = 0; j < 4; ++j) {
                float4 hv = hb[j * (H_F / 4) + k4];  // block-uniform 16B broadcast
                acc[j] = fmaf(hv.x, w0,
                         fmaf(hv.y, w1,
                         fmaf(hv.z, w2,
                         fmaf(hv.w, w3, acc[j]))));
            }
        }
#pragma unroll
        for (int j = 0; j < 4; ++j) {
            int n = n0 + j;
            xbuf[(size_t)n * (HEADS * H_F) + t] = acc[j];
            float vs = acc[j] * asv, vd = acc[j] * adv;
#pragma unroll
            for (int off = 32; off; off >>= 1) {
                vs += __shfl_xor(vs, off, 64);
                vd += __shfl_xor(vd, off, 64);
            }
            if (lane == 0) {
                ls[n * HEADS + wv] = vs;
                ld[n * HEADS + wv] = vd;
            }
        }
    }
}

__device__ __forceinline__ float lrelu_exp(float e) {
    e = (e > 0.f) ? e : NEG * e;
    return __expf(e);
}

// ---------------- edge pass 1: denom[dst,h] += exp(lrelu(ls[src]+ld[dst])) ----
__global__ void k_edge_denom(const int* __restrict__ src, const int* __restrict__ dst,
                             const float4* __restrict__ ls4, const float4* __restrict__ ld4,
                             float* __restrict__ den) {
    int i = blockIdx.x * blockDim.x + threadIdx.x;
    if (i >= EE + NN) return;
    int s, d;
    if (i < EE) { s = src[i]; d = dst[i]; } else { s = d = i - EE; }
    float4 a = ls4[s];
    float4 b = ld4[d];
    atomicAdd(&den[d * HEADS + 0], lrelu_exp(a.x + b.x));
    atomicAdd(&den[d * HEADS + 1], lrelu_exp(a.y + b.y));
    atomicAdd(&den[d * HEADS + 2], lrelu_exp(a.z + b.z));
    atomicAdd(&den[d * HEADS + 3], lrelu_exp(a.w + b.w));
}

// ---------------- edge pass 2: acc[dst,c] += (1/4) sum_h alpha[e,h]*x[src,h,c] --
// one wave per edge (lane = channel c), grid-stride over edges.
__global__ void k_edge_aggr(const int* __restrict__ src, const int* __restrict__ dst,
                            const float4* __restrict__ ls4, const float4* __restrict__ ld4,
                            const float4* __restrict__ den4, const float* __restrict__ xbuf,
                            float* __restrict__ accb, int totalWaves) {
    int lane = threadIdx.x & 63;
    int wave = (blockIdx.x * blockDim.x + threadIdx.x) >> 6;
    for (int e = wave; e < EE + NN; e += totalWaves) {
        int s, d;
        if (e < EE) { s = src[e]; d = dst[e]; } else { s = d = e - EE; }
        s = __builtin_amdgcn_readfirstlane(s);
        d = __builtin_amdgcn_readfirstlane(d);
        float4 a = ls4[s];
        float4 b = ld4[d];
        float4 dn = den4[d];
        float w0 = lrelu_exp(a.x + b.x) / (dn.x + 1e-16f) * 0.25f;
        float w1 = lrelu_exp(a.y + b.y) / (dn.y + 1e-16f) * 0.25f;
        float w2 = lrelu_exp(a.z + b.z) / (dn.z + 1e-16f) * 0.25f;
        float w3 = lrelu_exp(a.w + b.w) / (dn.w + 1e-16f) * 0.25f;
        const float* xp = xbuf + (size_t)s * (HEADS * H_F);
        float acc = w0 * xp[lane] + w1 * xp[64 + lane] + w2 * xp[128 + lane] + w3 * xp[192 + lane];
        atomicAdd(&accb[(size_t)d * H_F + lane], acc);
    }
}

// ---------------- finalize: h = relu(acc + b), in place, float4 --------------
__global__ void k_finalize(float* __restrict__ h, const float* __restrict__ bias) {
    int i = blockIdx.x * blockDim.x + threadIdx.x;  // float4 index
    if (i >= NN * (H_F / 4)) return;
    float4 v = ((float4*)h)[i];
    float4 b = ((const float4*)bias)[i & 15];
    v.x = fmaxf(v.x + b.x, 0.f);
    v.y = fmaxf(v.y + b.y, 0.f);
    v.z = fmaxf(v.z + b.z, 0.f);
    v.w = fmaxf(v.w + b.w, 0.f);
    ((float4*)h)[i] = v;
}

// ---------------- graph starts via binary search on sorted batch -------------
__global__ void k_starts(const int* __restrict__ batch, int* __restrict__ starts) {
    int g = threadIdx.x;
    if (g > GG) return;
    int lo = 0, hi = NN;
    while (lo < hi) {
        int mid = (lo + hi) >> 1;
        if (batch[mid] < g) lo = mid + 1; else hi = mid;
    }
    starts[g] = lo;
}

// ---------------- pooling: pooledT[c][g] = mean over nodes of graph g --------
__global__ void k_pool(const float* __restrict__ h, const int* __restrict__ starts,
                       float* __restrict__ pooledT) {
    int g = blockIdx.x;
    int s = starts[g], e = starts[g + 1];
    int t = threadIdx.x;
    int c = t & 63, j = t >> 6;
    float sum = 0.f;
    for (int n = s + j; n < e; n += 4) sum += h[(size_t)n * H_F + c];
    __shared__ float lds[256];
    lds[t] = sum;
    __syncthreads();
    if (j == 0) {
        float tot = lds[c] + lds[64 + c] + lds[128 + c] + lds[192 + c];
        int cnt = e - s;
        float inv = 1.0f / (float)(cnt > 0 ? cnt : 1);
        pooledT[c * GG + g] = tot * inv;
    }
}

// ---------------- final FC: out[g,o] = sum_c pooledT[c][g]*Wfc[c,o] + bfc[o] --
// __launch_bounds__(256) lets acc[64] live in VGPRs (no 64-reg cap spill).
__global__ __launch_bounds__(256) void k_fc(const float* __restrict__ pooledT,
                                            const float* __restrict__ Wfc,
                                            const float* __restrict__ bfc,
                                            float* __restrict__ out) {
    int o = blockIdx.x * blockDim.x + threadIdx.x;
    if (o >= OUT_F) return;
    float acc[GG];
#pragma unroll
    for (int g = 0; g < GG; ++g) acc[g] = 0.f;
    for (int c = 0; c < H_F; ++c) {
        float wvv = Wfc[(size_t)c * OUT_F + o];
        const float* pr = pooledT + c * GG;
#pragma unroll
        for (int g = 0; g < GG; ++g) acc[g] += pr[g] * wvv;
    }
    float bv = bfc[o];
    for (int g = 0; g < GG; ++g) out[(size_t)g * OUT_F + o] = acc[g] + bv;
}

extern "C" void kernel_launch(void* const* d_in, const int* in_sizes, int n_in,
                              void* d_out, int out_size, void* d_ws, size_t ws_size,
                              hipStream_t stream) {
    const float* x      = (const float*)d_in[0];
    const int*   eidx   = (const int*)d_in[1];
    const int*   batch  = (const int*)d_in[3];
    const float* W_emb  = (const float*)d_in[4];
    const float* b_emb  = (const float*)d_in[5];
    const float* W_fc   = (const float*)d_in[6];
    const float* b_fc   = (const float*)d_in[7];
    const float* Wl[3]   = {(const float*)d_in[8],  (const float*)d_in[12], (const float*)d_in[16]};
    const float* asl[3]  = {(const float*)d_in[9],  (const float*)d_in[13], (const float*)d_in[17]};
    const float* adl[3]  = {(const float*)d_in[10], (const float*)d_in[14], (const float*)d_in[18]};
    const float* bl[3]   = {(const float*)d_in[11], (const float*)d_in[15], (const float*)d_in[19]};

    const int* src = eidx;
    const int* dst = eidx + EE;

    // workspace carving (all float-aligned, total ~79 MB)
    float* xbuf    = (float*)d_ws;                     // N*256
    float* hA      = xbuf + (size_t)NN * 256;          // N*64
    float* hB      = hA + (size_t)NN * 64;             // N*64
    float* ls      = hB + (size_t)NN * 64;             // N*4
    float* ldb     = ls + (size_t)NN * 4;              // N*4
    float* den     = ldb + (size_t)NN * 4;             // N*4
    float* pooledT = den + (size_t)NN * 4;             // 64*64
    int*   starts  = (int*)(pooledT + GG * GG);        // 65

    k_emb<<<(NN + 31) / 32, 256, 0, stream>>>(x, W_emb, b_emb, hA);

    float* hcur = hA;
    float* hnext = hB;
    for (int l = 0; l < 3; ++l) {
        k_gemm_layer<<<(NN + 31) / 32, 256, 0, stream>>>(hcur, Wl[l], asl[l], adl[l],
                                                         xbuf, ls, ldb);
        hipMemsetAsync(den, 0, (size_t)NN * 4 * sizeof(float), stream);
        hipMemsetAsync(hnext, 0, (size_t)NN * 64 * sizeof(float), stream);
        k_edge_denom<<<(EE + NN + 255) / 256, 256, 0, stream>>>(
            src, dst, (const float4*)ls, (const float4*)ldb, den);
        const int aggrBlocks = 2048;  // 4 waves each -> 8192 waves, grid-stride
        k_edge_aggr<<<aggrBlocks, 256, 0, stream>>>(
            src, dst, (const float4*)ls, (const float4*)ldb, (const float4*)den,
            xbuf, hnext, aggrBlocks * 4);
        k_finalize<<<(NN * 16 + 255) / 256, 256, 0, stream>>>(hnext, bl[l]);
        float* tmp = hcur; hcur = hnext; hnext = tmp;
    }

    k_starts<<<1, 128, 0, stream>>>(batch, starts);
    k_pool<<<GG, 256, 0, stream>>>(hcur, starts, pooledT);
    k_fc<<<(OUT_F + 255) / 256, 256, 0, stream>>>(pooledT, W_fc, b_fc, (float*)d_out);
}

// Round 2
// 821.073 us; speedup vs baseline: 1.9374x; 1.9374x over previous
//
#include <hip/hip_runtime.h>

#define NN 50000
#define EE 500000
#define GG 64
#define IN_F 128
#define H_F 64
#define HEADS 4
#define OUT_F 326000
#define NEG 0.2f
#define SCAN_B 256
#define NBLK ((NN + SCAN_B - 1) / SCAN_B)   // 196

// ---------------- embedding GEMM: h0 = x @ W_emb + b_emb ----------------
// (round-1 version, verified fast: W in LDS, wave-uniform x row broadcasts)
__global__ __launch_bounds__(256) void k_emb(const float* __restrict__ x,
                                             const float* __restrict__ Wemb,
                                             const float* __restrict__ bemb,
                                             float* __restrict__ h0) {
    __shared__ float wlds[IN_F * H_F];  // [k][c], 32 KB
    int t = threadIdx.x;
#pragma unroll
    for (int i = 0; i < (IN_F * H_F) / (4 * 256); ++i)
        ((float4*)wlds)[t + 256 * i] = ((const float4*)Wemb)[t + 256 * i];
    __syncthreads();

    int c = t & 63, sub = t >> 6;
    int n0 = __builtin_amdgcn_readfirstlane(blockIdx.x * 32 + sub * 8);
    float bv = bemb[c];

    if (n0 + 8 <= NN) {
        const float4* xr = (const float4*)(x + (size_t)n0 * IN_F);
        float acc[8] = {0.f, 0.f, 0.f, 0.f, 0.f, 0.f, 0.f, 0.f};
        for (int k4 = 0; k4 < IN_F / 4; ++k4) {
            float w0 = wlds[(4 * k4 + 0) * H_F + c];
            float w1 = wlds[(4 * k4 + 1) * H_F + c];
            float w2 = wlds[(4 * k4 + 2) * H_F + c];
            float w3 = wlds[(4 * k4 + 3) * H_F + c];
#pragma unroll
            for (int j = 0; j < 8; ++j) {
                float4 xv = xr[j * (IN_F / 4) + k4];
                acc[j] = fmaf(xv.x, w0,
                         fmaf(xv.y, w1,
                         fmaf(xv.z, w2,
                         fmaf(xv.w, w3, acc[j]))));
            }
        }
#pragma unroll
        for (int j = 0; j < 8; ++j)
            h0[(size_t)(n0 + j) * H_F + c] = acc[j] + bv;
    } else {
        for (int j = 0; j < 8; ++j) {
            int n = n0 + j;
            if (n >= NN) break;
            const float* xrow = x + (size_t)n * IN_F;
            float a = 0.f;
            for (int k = 0; k < IN_F; ++k) a += xrow[k] * wlds[k * H_F + c];
            h0[(size_t)n * H_F + c] = a + bv;
        }
    }
}

// ---------------- per-layer GEMM (round-0 register-weight version, ~53 µs) ---
// block 256 threads = all 256 output cols of ONE node at a time; wave w = head w.
__global__ void k_gemm_layer(const float* __restrict__ h, const float* __restrict__ W,
                             const float* __restrict__ a_src, const float* __restrict__ a_dst,
                             float* __restrict__ xbuf, float* __restrict__ ls,
                             float* __restrict__ ld) {
    int t = threadIdx.x;
    int lane = t & 63, wv = t >> 6;
    float wreg[H_F];
#pragma unroll
    for (int k = 0; k < H_F; ++k) wreg[k] = W[k * (HEADS * H_F) + t];
    float asv = a_src[t], adv = a_dst[t];
    int base = blockIdx.x * 32;
    for (int i = 0; i < 32; ++i) {
        int n = base + i;
        if (n >= NN) return;
        const float* hr = h + (size_t)n * H_F;
        float acc = 0.f;
#pragma unroll
        for (int k = 0; k < H_F; ++k) acc += hr[k] * wreg[k];
        xbuf[(size_t)n * (HEADS * H_F) + t] = acc;
        float vs = acc * asv, vd = acc * adv;
#pragma unroll
        for (int off = 32; off; off >>= 1) {
            vs += __shfl_xor(vs, off, 64);
            vd += __shfl_xor(vd, off, 64);
        }
        if (lane == 0) {
            ls[n * HEADS + wv] = vs;
            ld[n * HEADS + wv] = vd;
        }
    }
}

__device__ __forceinline__ float lrelu_exp(float e) {
    e = (e > 0.f) ? e : NEG * e;
    return __expf(e);
}

// ================= CSR build (once per launch; graph static across layers) ====
// count in-degree (incl. self loops)
__global__ void k_count(const int* __restrict__ dst, int* __restrict__ cnt) {
    int i = blockIdx.x * blockDim.x + threadIdx.x;
    if (i >= EE + NN) return;
    int d = (i < EE) ? dst[i] : (i - EE);
    atomicAdd(&cnt[d], 1);
}

// block-local exclusive scan; emit block sums
__global__ void k_scan1(const int* __restrict__ cnt, int* __restrict__ excl,
                        int* __restrict__ bsum) {
    __shared__ int lds[SCAN_B];
    int t = threadIdx.x, i = blockIdx.x * SCAN_B + t;
    int v = (i < NN) ? cnt[i] : 0;
    lds[t] = v;
    __syncthreads();
    for (int off = 1; off < SCAN_B; off <<= 1) {
        int add = (t >= off) ? lds[t - off] : 0;
        __syncthreads();
        lds[t] += add;
        __syncthreads();
    }
    if (i < NN) excl[i] = lds[t] - v;
    if (t == SCAN_B - 1) bsum[blockIdx.x] = lds[t];
}

// scan the block sums (NBLK=196 <= 256), exclusive, in place
__global__ void k_scan2(int* __restrict__ bsum) {
    __shared__ int lds[SCAN_B];
    int t = threadIdx.x;
    int v = (t < NBLK) ? bsum[t] : 0;
    lds[t] = v;
    __syncthreads();
    for (int off = 1; off < SCAN_B; off <<= 1) {
        int add = (t >= off) ? lds[t - off] : 0;
        __syncthreads();
        lds[t] += add;
        __syncthreads();
    }
    if (t < NBLK) bsum[t] = lds[t] - v;
}

// combine -> row ptr + scatter cursor
__global__ void k_scan3(const int* __restrict__ excl, const int* __restrict__ bsum,
                        int* __restrict__ row, int* __restrict__ cursor) {
    int i = blockIdx.x * blockDim.x + threadIdx.x;
    if (i >= NN) return;
    int r = excl[i] + bsum[i / SCAN_B];
    row[i] = r;
    cursor[i] = r;
    if (i == 0) row[NN] = EE + NN;
}

// scatter src ids into CSR slots (order within a node irrelevant for sums)
__global__ void k_scatter(const int* __restrict__ src, const int* __restrict__ dst,
                          int* __restrict__ cursor, int* __restrict__ csr_src) {
    int i = blockIdx.x * blockDim.x + threadIdx.x;
    if (i >= EE + NN) return;
    int s, d;
    if (i < EE) { s = src[i]; d = dst[i]; } else { s = d = i - EE; }
    int pos = atomicAdd(&cursor[d], 1);
    csr_src[pos] = s;
}

// ========== fused softmax + aggregation + bias + relu, one wave per node ======
// out[d,c] = relu( 0.25 * sum_h ( sum_e ex_h(e) * x[s_e,h,c] ) / (1e-16 + sum_e ex_h(e)) + b[c] )
// ex_h(e) = exp(lrelu(ls[s_e,h] + ld[d,h]))  -- identical math to alpha-normalization.
__global__ __launch_bounds__(256) void k_aggr_csr(const int* __restrict__ row,
                                                  const int* __restrict__ csr_src,
                                                  const float4* __restrict__ ls4,
                                                  const float4* __restrict__ ld4,
                                                  const float* __restrict__ xbuf,
                                                  const float* __restrict__ bias,
                                                  float* __restrict__ hout) {
    int t = threadIdx.x;
    int lane = t & 63, wv = t >> 6;
    int d = blockIdx.x * 4 + wv;
    if (d >= NN) return;
    int r0 = row[d], r1 = row[d + 1];
    float4 bld = ld4[d];  // wave-uniform
    float den0 = 1e-16f, den1 = 1e-16f, den2 = 1e-16f, den3 = 1e-16f;
    float a0 = 0.f, a1 = 0.f, a2 = 0.f, a3 = 0.f;
    for (int j = r0; j < r1; ++j) {
        int s = __builtin_amdgcn_readfirstlane(csr_src[j]);
        float4 als = ls4[s];
        float e0 = lrelu_exp(als.x + bld.x);
        float e1 = lrelu_exp(als.y + bld.y);
        float e2 = lrelu_exp(als.z + bld.z);
        float e3 = lrelu_exp(als.w + bld.w);
        den0 += e0; den1 += e1; den2 += e2; den3 += e3;
        const float* xp = xbuf + (size_t)s * (HEADS * H_F);
        a0 = fmaf(e0, xp[lane], a0);
        a1 = fmaf(e1, xp[64 + lane], a1);
        a2 = fmaf(e2, xp[128 + lane], a2);
        a3 = fmaf(e3, xp[192 + lane], a3);
    }
    float res = 0.25f * (a0 / den0 + a1 / den1 + a2 / den2 + a3 / den3);
    res = fmaxf(res + bias[lane], 0.f);
    hout[(size_t)d * H_F + lane] = res;
}

// ---------------- graph starts via binary search on sorted batch -------------
__global__ void k_starts(const int* __restrict__ batch, int* __restrict__ starts) {
    int g = threadIdx.x;
    if (g > GG) return;
    int lo = 0, hi = NN;
    while (lo < hi) {
        int mid = (lo + hi) >> 1;
        if (batch[mid] < g) lo = mid + 1; else hi = mid;
    }
    starts[g] = lo;
}

// ---------------- pooling: pooledT[c][g] = mean over nodes of graph g --------
__global__ void k_pool(const float* __restrict__ h, const int* __restrict__ starts,
                       float* __restrict__ pooledT) {
    int g = blockIdx.x;
    int s = starts[g], e = starts[g + 1];
    int t = threadIdx.x;
    int c = t & 63, j = t >> 6;
    float sum = 0.f;
    for (int n = s + j; n < e; n += 4) sum += h[(size_t)n * H_F + c];
    __shared__ float lds[256];
    lds[t] = sum;
    __syncthreads();
    if (j == 0) {
        float tot = lds[c] + lds[64 + c] + lds[128 + c] + lds[192 + c];
        int cnt = e - s;
        float inv = 1.0f / (float)(cnt > 0 ? cnt : 1);
        pooledT[c * GG + g] = tot * inv;
    }
}

// ---------------- final FC: out[g,o] = sum_c pooledT[c][g]*Wfc[c,o] + bfc[o] --
__global__ __launch_bounds__(256) void k_fc(const float* __restrict__ pooledT,
                                            const float* __restrict__ Wfc,
                                            const float* __restrict__ bfc,
                                            float* __restrict__ out) {
    int o = blockIdx.x * blockDim.x + threadIdx.x;
    if (o >= OUT_F) return;
    float acc[GG];
#pragma unroll
    for (int g = 0; g < GG; ++g) acc[g] = 0.f;
    for (int c = 0; c < H_F; ++c) {
        float wvv = Wfc[(size_t)c * OUT_F + o];
        const float* pr = pooledT + c * GG;
#pragma unroll
        for (int g = 0; g < GG; ++g) acc[g] += pr[g] * wvv;
    }
    float bv = bfc[o];
    for (int g = 0; g < GG; ++g) out[(size_t)g * OUT_F + o] = acc[g] + bv;
}

extern "C" void kernel_launch(void* const* d_in, const int* in_sizes, int n_in,
                              void* d_out, int out_size, void* d_ws, size_t ws_size,
                              hipStream_t stream) {
    const float* x      = (const float*)d_in[0];
    const int*   eidx   = (const int*)d_in[1];
    const int*   batch  = (const int*)d_in[3];
    const float* W_emb  = (const float*)d_in[4];
    const float* b_emb  = (const float*)d_in[5];
    const float* W_fc   = (const float*)d_in[6];
    const float* b_fc   = (const float*)d_in[7];
    const float* Wl[3]   = {(const float*)d_in[8],  (const float*)d_in[12], (const float*)d_in[16]};
    const float* asl[3]  = {(const float*)d_in[9],  (const float*)d_in[13], (const float*)d_in[17]};
    const float* adl[3]  = {(const float*)d_in[10], (const float*)d_in[14], (const float*)d_in[18]};
    const float* bl[3]   = {(const float*)d_in[11], (const float*)d_in[15], (const float*)d_in[19]};

    const int* src = eidx;
    const int* dst = eidx + EE;

    // workspace carving (~81.5 MB)
    float* xbuf    = (float*)d_ws;                     // N*256
    float* hA      = xbuf + (size_t)NN * 256;          // N*64
    float* hB      = hA + (size_t)NN * 64;             // N*64
    float* ls      = hB + (size_t)NN * 64;             // N*4
    float* ldb     = ls + (size_t)NN * 4;              // N*4
    float* pooledT = ldb + (size_t)NN * 4;             // 64*64
    int*   starts  = (int*)(pooledT + GG * GG);        // 65 (pad to 128)
    int*   cnt     = starts + 128;                     // N
    int*   excl    = cnt + NN;                         // N
    int*   bsum    = excl + NN;                        // 256
    int*   row     = bsum + 256;                       // N+1 (pad to N+4)
    int*   cursor  = row + NN + 4;                     // N
    int*   csr_src = cursor + NN;                      // E+N

    // ---- CSR build (once; graph identical for all 3 layers) ----
    hipMemsetAsync(cnt, 0, (size_t)NN * sizeof(int), stream);
    k_count<<<(EE + NN + 255) / 256, 256, 0, stream>>>(dst, cnt);
    k_scan1<<<NBLK, SCAN_B, 0, stream>>>(cnt, excl, bsum);
    k_scan2<<<1, SCAN_B, 0, stream>>>(bsum);
    k_scan3<<<(NN + 255) / 256, 256, 0, stream>>>(excl, bsum, row, cursor);
    k_scatter<<<(EE + NN + 255) / 256, 256, 0, stream>>>(src, dst, cursor, csr_src);

    k_emb<<<(NN + 31) / 32, 256, 0, stream>>>(x, W_emb, b_emb, hA);

    float* hcur = hA;
    float* hnext = hB;
    for (int l = 0; l < 3; ++l) {
        k_gemm_layer<<<(NN + 31) / 32, 256, 0, stream>>>(hcur, Wl[l], asl[l], adl[l],
                                                         xbuf, ls, ldb);
        k_aggr_csr<<<(NN + 3) / 4, 256, 0, stream>>>(row, csr_src,
                                                     (const float4*)ls, (const float4*)ldb,
                                                     xbuf, bl[l], hnext);
        float* tmp = hcur; hcur = hnext; hnext = tmp;
    }

    k_starts<<<1, 128, 0, stream>>>(batch, starts);
    k_pool<<<GG, 256, 0, stream>>>(hcur, starts, pooledT);
    k_fc<<<(OUT_F + 255) / 256, 256, 0, stream>>>(pooledT, W_fc, b_fc, (float*)d_out);
}